// Round 7
// baseline (123.338 us; speedup 1.0000x reference)
//
#include <hip/hip_runtime.h>
#include <math.h>

#define B_TOT    2048
#define D_DIM    128
#define C_TOT    100000
#define MARGIN   0.5f
#define EPS_C    1e-7f
#define LN2F     0.6931471805599453f
#define S_LOG2E  92.33248261689366f   // 64 * log2(e)
#define MU_COEF  34.929f              // S_LOG2E * 4.2801/sqrt(128)
#define MU_PAD   20.0f
#define CLAMP_HI 124.0f

#define NCHUNK   125                  // col chunks, 800 cols each
#define GPC      50                   // 16-col groups per chunk
#define NRBLK    16                   // row blocks, 128 rows each

#define PREP_A   391
#define PREP_B   128
#define PREP_C   512

typedef __attribute__((ext_vector_type(8))) _Float16 f16x8;
typedef __attribute__((ext_vector_type(4))) float    f32x4;

#define EXP2(x) __builtin_amdgcn_exp2f(x)

// ---- Kernel 1: fused prep (3 independent phases by block range) ------------
// A: single-pass W read -> NORMALIZED f16 Whf in MFMA-fragment order.
//    Group g (cols g*16..+15) is a contiguous 4 KB block: elem off =
//    g*2048 + t*512 + lq*128 + lc*8 + e = Wn[k=t*32+lq*8+e][col=g*16+lc].
// B: emb -> f16 scaled by 64*log2e.
// C: per-row exact fp32 target logit + margin + mhat from ||emb||.
__global__ __launch_bounds__(256) void prep_kernel(
    const float* __restrict__ W, const float* __restrict__ emb,
    const int* __restrict__ labels,
    _Float16* __restrict__ Whf, _Float16* __restrict__ Ahf,
    float2* __restrict__ tval2, float* __restrict__ mneg)
{
    const int bx = blockIdx.x, tid = threadIdx.x;
    if (bx < PREP_A) {
        int c = bx * 256 + tid;
        if (c >= C_TOT) return;
        int g = c >> 4, lc = c & 15;
        f16x8 buf[16];
        float ss = 0.f;
#pragma unroll
        for (int t = 0; t < 4; ++t)
#pragma unroll
            for (int lq = 0; lq < 4; ++lq) {
                f16x8 v;
#pragma unroll
                for (int h = 0; h < 8; ++h) {
                    float w = W[(size_t)(t * 32 + lq * 8 + h) * C_TOT + c];
                    ss = fmaf(w, w, ss);
                    v[h] = (_Float16)w;
                }
                buf[t * 4 + lq] = v;
            }
        float iv = 1.f / fmaxf(sqrtf(ss), 1e-12f);
        _Float16* base = Whf + ((size_t)g * 2048 + lc * 8);
#pragma unroll
        for (int t = 0; t < 4; ++t)
#pragma unroll
            for (int lq = 0; lq < 4; ++lq) {
                f16x8 v = buf[t * 4 + lq];
                f16x8 o;
#pragma unroll
                for (int h = 0; h < 8; ++h)
                    o[h] = (_Float16)((float)v[h] * iv);
                *(f16x8*)(base + t * 512 + lq * 128) = o;
            }
    } else if (bx < PREP_A + PREP_B) {
        int i = (bx - PREP_A) * 256 + tid;
        float4 a = ((const float4*)emb)[2 * i];
        float4 b = ((const float4*)emb)[2 * i + 1];
        f16x8 v;
        v[0] = (_Float16)(a.x * S_LOG2E); v[1] = (_Float16)(a.y * S_LOG2E);
        v[2] = (_Float16)(a.z * S_LOG2E); v[3] = (_Float16)(a.w * S_LOG2E);
        v[4] = (_Float16)(b.x * S_LOG2E); v[5] = (_Float16)(b.y * S_LOG2E);
        v[6] = (_Float16)(b.z * S_LOG2E); v[7] = (_Float16)(b.w * S_LOG2E);
        ((f16x8*)Ahf)[i] = v;
    } else {
        int row  = (bx - PREP_A - PREP_B) * 4 + (tid >> 6);
        int lane = tid & 63;
        int lab  = labels[row];
        float e0 = emb[row * D_DIM + lane];
        float e1 = emb[row * D_DIM + 64 + lane];
        float w0 = W[(size_t)lane * C_TOT + lab];
        float w1 = W[(size_t)(64 + lane) * C_TOT + lab];
        float dot = e0 * w0 + e1 * w1;
        float sw  = w0 * w0 + w1 * w1;
        float se  = e0 * e0 + e1 * e1;
#pragma unroll
        for (int off = 32; off > 0; off >>= 1) {
            dot += __shfl_down(dot, off, 64);
            sw  += __shfl_down(sw,  off, 64);
            se  += __shfl_down(se,  off, 64);
        }
        if (lane == 0) {
            float ivl  = 1.f / fmaxf(sqrtf(sw), 1e-12f);
            float tdot = dot * ivl;
            float tc   = fminf(fmaxf(tdot, -1.f + EPS_C), 1.f - EPS_C);
            float tm   = cosf(acosf(tc) + MARGIN);
            float mh   = MU_COEF * sqrtf(se) + MU_PAD;
            tval2[row] = make_float2(tdot * S_LOG2E, tm * S_LOG2E);
            mneg[row]  = -mh;
        }
    }
}

// ---- Kernel 2: MFMA GEMM + fused fixed-shift sum-of-exp2 -------------------
// grid 2000 (XCD-swizzled); 4 waves x 32 rows, NO LDS, NO barriers.
// B streams global->VGPR through a 3-buffer rotating register pipeline
// (compiler-counted vmcnt, ~2-3 groups in flight). Block's 4 waves read
// identical B addresses -> L1 merge; row-blocks share chunk panel in XCD L2.
__global__ __launch_bounds__(256) void gemm_lse(
    const _Float16* __restrict__ Ahf, const _Float16* __restrict__ Whf,
    const float* __restrict__ mneg, float* __restrict__ partial)
{
    const int b  = blockIdx.x;
    const int L  = (b & 7) * 250 + (b >> 3);   // bijective XCD swizzle (2000=8*250)
    const int chunk = L >> 4;                  // 0..124
    const int rb    = L & 15;
    const int tid = threadIdx.x;
    const int w   = tid >> 6;
    const int l   = tid & 63;
    const int lc  = l & 15;
    const int lq  = l >> 4;
    const int r0  = rb * 128 + w * 32;

    // A fragments: row r0+rt*16+lc, k = t*32 + lq*8 + e (resident)
    f16x8 afrag[2][4];
#pragma unroll
    for (int rt = 0; rt < 2; ++rt)
#pragma unroll
        for (int t = 0; t < 4; ++t)
            afrag[rt][t] = *(const f16x8*)&Ahf[(size_t)(r0 + rt * 16 + lc) * D_DIM
                                               + t * 32 + lq * 8];
    // per-row -mhat constants (acc reg j of half rt <-> row r0+rt*16+lq*4+j)
    float mn[8];
#pragma unroll
    for (int rt = 0; rt < 2; ++rt)
#pragma unroll
        for (int j = 0; j < 4; ++j)
            mn[rt * 4 + j] = mneg[r0 + rt * 16 + lq * 4 + j];

    // lane-fixed B base: group g, k-step t lives at bbase + g*2048 + t*512
    const _Float16* bbase = Whf + (size_t)chunk * (GPC * 2048) + l * 8;

    float s[8];
#pragma unroll
    for (int j = 0; j < 8; ++j) s[j] = 0.f;

    auto loadB = [&](f16x8 bf[4], int g) {
        const _Float16* p = bbase + (size_t)g * 2048;
#pragma unroll
        for (int t = 0; t < 4; ++t) bf[t] = *(const f16x8*)(p + t * 512);
    };

    auto compute = [&](const f16x8 bf[4]) {
        f32x4 acc0 = {0.f, 0.f, 0.f, 0.f};
        f32x4 acc1 = {0.f, 0.f, 0.f, 0.f};
#pragma unroll
        for (int t = 0; t < 4; ++t) {
            acc0 = __builtin_amdgcn_mfma_f32_16x16x32_f16(afrag[0][t], bf[t], acc0, 0, 0, 0);
            acc1 = __builtin_amdgcn_mfma_f32_16x16x32_f16(afrag[1][t], bf[t], acc1, 0, 0, 0);
        }
        float v[8] = {acc0[0], acc0[1], acc0[2], acc0[3],
                      acc1[0], acc1[1], acc1[2], acc1[3]};
#pragma unroll
        for (int j = 0; j < 8; ++j) {
            float arg = fminf(v[j] + mn[j], CLAMP_HI);
            s[j] += EXP2(arg);
        }
    };

    // 3-buffer rotating pipeline over 50 groups; Whf is padded so the
    // over-prefetch at the tail (up to group index 50) reads valid memory.
    f16x8 b0[4], b1[4], b2[4];
    loadB(b0, 0); loadB(b1, 1); loadB(b2, 2);
#pragma unroll 1
    for (int k = 0; k < 16; ++k) {         // groups 0..47
        int g = k * 3;
        compute(b0); loadB(b0, g + 3);
        compute(b1); loadB(b1, g + 4);
        compute(b2); loadB(b2, g + 5);
    }
    compute(b0);                            // group 48
    compute(b1);                            // group 49

    // pure-sum reduce across the 16 col-lanes (shared mhat -> no max merge)
#pragma unroll
    for (int off = 1; off < 16; off <<= 1)
#pragma unroll
        for (int j = 0; j < 8; ++j) s[j] += __shfl_xor(s[j], off, 64);

    if (lc == 0) {
#pragma unroll
        for (int rt = 0; rt < 2; ++rt)
#pragma unroll
            for (int i = 0; i < 4; ++i) {
                int grow = r0 + rt * 16 + lq * 4 + i;
                partial[(size_t)chunk * B_TOT + grow] = s[rt * 4 + i];
            }
    }
}

// ---- Kernel 3: per-row merge + target correction -> 16 block partials ------
__global__ __launch_bounds__(128) void finalize1(
    const float* __restrict__ partial, const float2* __restrict__ tval2,
    const float* __restrict__ mneg, float* __restrict__ blockpart)
{
    __shared__ float red[2];
    int r = blockIdx.x * 128 + threadIdx.x;
    float S = 0.f;
#pragma unroll 1
    for (int k = 0; k < NCHUNK; ++k) S += partial[(size_t)k * B_TOT + r];
    float  mh = -mneg[r];
    float2 t  = tval2[r];
    S += EXP2(t.y - mh) - EXP2(t.x - mh);
    S  = fmaxf(S, 1e-30f);
    float loss = LN2F * (mh + log2f(S) - t.y);
#pragma unroll
    for (int off = 32; off > 0; off >>= 1) loss += __shfl_down(loss, off, 64);
    int lane = threadIdx.x & 63, wv = threadIdx.x >> 6;
    if (lane == 0) red[wv] = loss;
    __syncthreads();
    if (threadIdx.x == 0) blockpart[blockIdx.x] = red[0] + red[1];
}

// ---- Kernel 4: 16 partials -> mean loss ------------------------------------
__global__ __launch_bounds__(64) void finalize2(
    const float* __restrict__ blockpart, float* __restrict__ out)
{
    int t = threadIdx.x;
    float v = (t < 16) ? blockpart[t] : 0.f;
#pragma unroll
    for (int off = 32; off > 0; off >>= 1) v += __shfl_down(v, off, 64);
    if (t == 0) out[0] = v / (float)B_TOT;
}

// ---- launch ----------------------------------------------------------------
extern "C" void kernel_launch(void* const* d_in, const int* in_sizes, int n_in,
                              void* d_out, int out_size, void* d_ws, size_t ws_size,
                              hipStream_t stream)
{
    const float* emb    = (const float*)d_in[0];
    const int*   labels = (const int*)  d_in[1];
    const float* W      = (const float*)d_in[2];

    char* p = (char*)d_ws;
    _Float16* Whf  = (_Float16*)p;
    p += ((size_t)C_TOT / 16 + 4) * 2048 * 2;                        // 25.6 MB + 16 KB pad
    _Float16* Ahf  = (_Float16*)p;  p += (size_t)B_TOT * D_DIM * 2;  // 512 KB
    float2*   tv2  = (float2*)p;    p += (size_t)B_TOT * 8;          // 16 KB
    float*    mneg = (float*)p;     p += (size_t)B_TOT * 4;          // 8 KB
    float*    part = (float*)p;     p += (size_t)NCHUNK * B_TOT * 4; // 1 MB
    float*    bpar = (float*)p;
    float*    out  = (float*)d_out;

    hipLaunchKernelGGL(prep_kernel, dim3(PREP_A + PREP_B + PREP_C), dim3(256), 0, stream,
                       W, emb, labels, Whf, Ahf, tv2, mneg);
    hipLaunchKernelGGL(gemm_lse, dim3(NCHUNK * NRBLK), dim3(256), 0, stream,
                       Ahf, Whf, mneg, part);
    hipLaunchKernelGGL(finalize1, dim3(B_TOT / 128), dim3(128), 0, stream,
                       part, tv2, mneg, bpar);
    hipLaunchKernelGGL(finalize2, dim3(1), dim3(64), 0, stream,
                       bpar, out);
}

// Round 8
// 120.352 us; speedup vs baseline: 1.0248x; 1.0248x over previous
//
#include <hip/hip_runtime.h>
#include <math.h>

#define B_TOT    2048
#define D_DIM    128
#define C_TOT    100000
#define MARGIN   0.5f
#define EPS_C    1e-7f
#define LN2F     0.6931471805599453f
#define S_LOG2E  92.33248261689366f   // 64 * log2(e)
#define MU_COEF  34.929f              // S_LOG2E * 4.2801/sqrt(128)
#define MU_PAD   20.0f
#define CLAMP_HI 124.0f

#define NCHUNK   125                  // col chunks, 800 cols each
#define GPC      50                   // 16-col groups per chunk
#define NRBLK    8                    // row blocks, 256 rows each

#define PREP_A   391
#define PREP_B   128
#define PREP_C   512

typedef __attribute__((ext_vector_type(8))) _Float16 f16x8;
typedef __attribute__((ext_vector_type(4))) float    f32x4;

#define EXP2(x) __builtin_amdgcn_exp2f(x)

// ---- Kernel 1: fused prep (3 independent phases by block range) ------------
// A: single-pass W read -> NORMALIZED f16 Whf in MFMA-fragment order.
//    Group g (cols g*16..+15) is a contiguous 4 KB block: elem off =
//    g*2048 + t*512 + lq*128 + lc*8 + e = Wn[k=t*32+lq*8+e][col=g*16+lc].
// B: emb -> f16 scaled by 64*log2e.
// C: per-row exact fp32 target logit + margin + mhat from ||emb||.
__global__ __launch_bounds__(256) void prep_kernel(
    const float* __restrict__ W, const float* __restrict__ emb,
    const int* __restrict__ labels,
    _Float16* __restrict__ Whf, _Float16* __restrict__ Ahf,
    float2* __restrict__ tval2, float* __restrict__ mneg)
{
    const int bx = blockIdx.x, tid = threadIdx.x;
    if (bx < PREP_A) {
        int c = bx * 256 + tid;
        if (c >= C_TOT) return;
        int g = c >> 4, lc = c & 15;
        f16x8 buf[16];
        float ss = 0.f;
#pragma unroll
        for (int t = 0; t < 4; ++t)
#pragma unroll
            for (int lq = 0; lq < 4; ++lq) {
                f16x8 v;
#pragma unroll
                for (int h = 0; h < 8; ++h) {
                    float w = W[(size_t)(t * 32 + lq * 8 + h) * C_TOT + c];
                    ss = fmaf(w, w, ss);
                    v[h] = (_Float16)w;
                }
                buf[t * 4 + lq] = v;
            }
        float iv = 1.f / fmaxf(sqrtf(ss), 1e-12f);
        _Float16* base = Whf + ((size_t)g * 2048 + lc * 8);
#pragma unroll
        for (int t = 0; t < 4; ++t)
#pragma unroll
            for (int lq = 0; lq < 4; ++lq) {
                f16x8 v = buf[t * 4 + lq];
                f16x8 o;
#pragma unroll
                for (int h = 0; h < 8; ++h)
                    o[h] = (_Float16)((float)v[h] * iv);
                *(f16x8*)(base + t * 512 + lq * 128) = o;
            }
    } else if (bx < PREP_A + PREP_B) {
        int i = (bx - PREP_A) * 256 + tid;
        float4 a = ((const float4*)emb)[2 * i];
        float4 b = ((const float4*)emb)[2 * i + 1];
        f16x8 v;
        v[0] = (_Float16)(a.x * S_LOG2E); v[1] = (_Float16)(a.y * S_LOG2E);
        v[2] = (_Float16)(a.z * S_LOG2E); v[3] = (_Float16)(a.w * S_LOG2E);
        v[4] = (_Float16)(b.x * S_LOG2E); v[5] = (_Float16)(b.y * S_LOG2E);
        v[6] = (_Float16)(b.z * S_LOG2E); v[7] = (_Float16)(b.w * S_LOG2E);
        ((f16x8*)Ahf)[i] = v;
    } else {
        int row  = (bx - PREP_A - PREP_B) * 4 + (tid >> 6);
        int lane = tid & 63;
        int lab  = labels[row];
        float e0 = emb[row * D_DIM + lane];
        float e1 = emb[row * D_DIM + 64 + lane];
        float w0 = W[(size_t)lane * C_TOT + lab];
        float w1 = W[(size_t)(64 + lane) * C_TOT + lab];
        float dot = e0 * w0 + e1 * w1;
        float sw  = w0 * w0 + w1 * w1;
        float se  = e0 * e0 + e1 * e1;
#pragma unroll
        for (int off = 32; off > 0; off >>= 1) {
            dot += __shfl_down(dot, off, 64);
            sw  += __shfl_down(sw,  off, 64);
            se  += __shfl_down(se,  off, 64);
        }
        if (lane == 0) {
            float ivl  = 1.f / fmaxf(sqrtf(sw), 1e-12f);
            float tdot = dot * ivl;
            float tc   = fminf(fmaxf(tdot, -1.f + EPS_C), 1.f - EPS_C);
            float tm   = cosf(acosf(tc) + MARGIN);
            float mh   = MU_COEF * sqrtf(se) + MU_PAD;
            tval2[row] = make_float2(tdot * S_LOG2E, tm * S_LOG2E);
            mneg[row]  = -mh;
        }
    }
}

// ---- Kernel 2: MFMA GEMM + fused fixed-shift sum-of-exp2 -------------------
// grid 1000 (XCD-swizzled); 8 waves x 32 rows = 256 rows/block. NO LDS, NO
// barriers: B streams global->VGPR through a 3-buffer rotating register
// pipeline (compiler-counted vmcnt). 512-thr blocks for dispatcher packing
// (R5 showed 8-wave WGs reach ~61% occupancy vs 26% for 4-wave); plain
// launch_bounds(512) -> no VGPR cap -> no scratch spill (R5's failure).
__global__ __launch_bounds__(512) void gemm_lse(
    const _Float16* __restrict__ Ahf, const _Float16* __restrict__ Whf,
    const float* __restrict__ mneg, float* __restrict__ partial)
{
    const int b  = blockIdx.x;
    const int L  = (b & 7) * 125 + (b >> 3);   // bijective XCD swizzle (1000=8*125)
    const int chunk = L >> 3;                  // 0..124
    const int rb    = L & 7;
    const int tid = threadIdx.x;
    const int w   = tid >> 6;
    const int l   = tid & 63;
    const int lc  = l & 15;
    const int lq  = l >> 4;
    const int r0  = rb * 256 + w * 32;

    // A fragments: row r0+rt*16+lc, k = t*32 + lq*8 + e (resident)
    f16x8 afrag[2][4];
#pragma unroll
    for (int rt = 0; rt < 2; ++rt)
#pragma unroll
        for (int t = 0; t < 4; ++t)
            afrag[rt][t] = *(const f16x8*)&Ahf[(size_t)(r0 + rt * 16 + lc) * D_DIM
                                               + t * 32 + lq * 8];
    // per-row -mhat constants (acc reg j of half rt <-> row r0+rt*16+lq*4+j)
    float mn[8];
#pragma unroll
    for (int rt = 0; rt < 2; ++rt)
#pragma unroll
        for (int j = 0; j < 4; ++j)
            mn[rt * 4 + j] = mneg[r0 + rt * 16 + lq * 4 + j];

    // lane-fixed B base: group g, k-step t lives at bbase + g*2048 + t*512
    const _Float16* bbase = Whf + (size_t)chunk * (GPC * 2048) + l * 8;

    float s[8];
#pragma unroll
    for (int j = 0; j < 8; ++j) s[j] = 0.f;

    auto loadB = [&](f16x8 bf[4], int g) {
        const _Float16* p = bbase + (size_t)g * 2048;
#pragma unroll
        for (int t = 0; t < 4; ++t) bf[t] = *(const f16x8*)(p + t * 512);
    };

    auto compute = [&](const f16x8 bf[4]) {
        f32x4 acc0 = {0.f, 0.f, 0.f, 0.f};
        f32x4 acc1 = {0.f, 0.f, 0.f, 0.f};
#pragma unroll
        for (int t = 0; t < 4; ++t) {
            acc0 = __builtin_amdgcn_mfma_f32_16x16x32_f16(afrag[0][t], bf[t], acc0, 0, 0, 0);
            acc1 = __builtin_amdgcn_mfma_f32_16x16x32_f16(afrag[1][t], bf[t], acc1, 0, 0, 0);
        }
        float v[8] = {acc0[0], acc0[1], acc0[2], acc0[3],
                      acc1[0], acc1[1], acc1[2], acc1[3]};
#pragma unroll
        for (int j = 0; j < 8; ++j) {
            float arg = fminf(v[j] + mn[j], CLAMP_HI);
            s[j] += EXP2(arg);
        }
    };

    // 3-buffer rotating pipeline over 50 groups; Whf is padded so the
    // over-prefetch at the tail (up to group index 50) reads valid memory.
    f16x8 b0[4], b1[4], b2[4];
    loadB(b0, 0); loadB(b1, 1); loadB(b2, 2);
#pragma unroll 1
    for (int k = 0; k < 16; ++k) {         // groups 0..47
        int g = k * 3;
        compute(b0); loadB(b0, g + 3);
        compute(b1); loadB(b1, g + 4);
        compute(b2); loadB(b2, g + 5);
    }
    compute(b0);                            // group 48
    compute(b1);                            // group 49

    // pure-sum reduce across the 16 col-lanes (shared mhat -> no max merge)
#pragma unroll
    for (int off = 1; off < 16; off <<= 1)
#pragma unroll
        for (int j = 0; j < 8; ++j) s[j] += __shfl_xor(s[j], off, 64);

    if (lc == 0) {
#pragma unroll
        for (int rt = 0; rt < 2; ++rt)
#pragma unroll
            for (int i = 0; i < 4; ++i) {
                int grow = r0 + rt * 16 + lq * 4 + i;
                partial[(size_t)chunk * B_TOT + grow] = s[rt * 4 + i];
            }
    }
}

// ---- Kernel 3: per-row merge + target correction -> 16 block partials ------
__global__ __launch_bounds__(128) void finalize1(
    const float* __restrict__ partial, const float2* __restrict__ tval2,
    const float* __restrict__ mneg, float* __restrict__ blockpart)
{
    __shared__ float red[2];
    int r = blockIdx.x * 128 + threadIdx.x;
    float S = 0.f;
#pragma unroll 1
    for (int k = 0; k < NCHUNK; ++k) S += partial[(size_t)k * B_TOT + r];
    float  mh = -mneg[r];
    float2 t  = tval2[r];
    S += EXP2(t.y - mh) - EXP2(t.x - mh);
    S  = fmaxf(S, 1e-30f);
    float loss = LN2F * (mh + log2f(S) - t.y);
#pragma unroll
    for (int off = 32; off > 0; off >>= 1) loss += __shfl_down(loss, off, 64);
    int lane = threadIdx.x & 63, wv = threadIdx.x >> 6;
    if (lane == 0) red[wv] = loss;
    __syncthreads();
    if (threadIdx.x == 0) blockpart[blockIdx.x] = red[0] + red[1];
}

// ---- Kernel 4: 16 partials -> mean loss ------------------------------------
__global__ __launch_bounds__(64) void finalize2(
    const float* __restrict__ blockpart, float* __restrict__ out)
{
    int t = threadIdx.x;
    float v = (t < 16) ? blockpart[t] : 0.f;
#pragma unroll
    for (int off = 32; off > 0; off >>= 1) v += __shfl_down(v, off, 64);
    if (t == 0) out[0] = v / (float)B_TOT;
}

// ---- launch ----------------------------------------------------------------
extern "C" void kernel_launch(void* const* d_in, const int* in_sizes, int n_in,
                              void* d_out, int out_size, void* d_ws, size_t ws_size,
                              hipStream_t stream)
{
    const float* emb    = (const float*)d_in[0];
    const int*   labels = (const int*)  d_in[1];
    const float* W      = (const float*)d_in[2];

    char* p = (char*)d_ws;
    _Float16* Whf  = (_Float16*)p;
    p += ((size_t)C_TOT / 16 + 4) * 2048 * 2;                        // 25.6 MB + 16 KB pad
    _Float16* Ahf  = (_Float16*)p;  p += (size_t)B_TOT * D_DIM * 2;  // 512 KB
    float2*   tv2  = (float2*)p;    p += (size_t)B_TOT * 8;          // 16 KB
    float*    mneg = (float*)p;     p += (size_t)B_TOT * 4;          // 8 KB
    float*    part = (float*)p;     p += (size_t)NCHUNK * B_TOT * 4; // 1 MB
    float*    bpar = (float*)p;
    float*    out  = (float*)d_out;

    hipLaunchKernelGGL(prep_kernel, dim3(PREP_A + PREP_B + PREP_C), dim3(256), 0, stream,
                       W, emb, labels, Whf, Ahf, tv2, mneg);
    hipLaunchKernelGGL(gemm_lse, dim3(NCHUNK * NRBLK), dim3(512), 0, stream,
                       Ahf, Whf, mneg, part);
    hipLaunchKernelGGL(finalize1, dim3(B_TOT / 128), dim3(128), 0, stream,
                       part, tv2, mneg, bpar);
    hipLaunchKernelGGL(finalize2, dim3(1), dim3(64), 0, stream,
                       bpar, out);
}